// Round 1
// baseline (471.886 us; speedup 1.0000x reference)
//
#include <hip/hip_runtime.h>
#include <math.h>

// VMamba SS2D fused pipeline for MI355X.
// B=4, C_IN=64, D=128, D4=512, N=16, H=W=64, L=4096.
// Layouts: all intermediates channel-last (b, p, c) for coalescing.

#define LL   4096
#define NCH  64      // chunks
#define TCH  64      // chunk length

__device__ __forceinline__ int tauf(int t) { return ((t & 63) << 6) | (t >> 6); }

// ---------------- K1: in_proj GEMM  xz[b,p,e] = sum_c x[b,c,p]*W[e,c]+bias ----
__global__ __launch_bounds__(256) void k_inproj(const float* __restrict__ x,
    const float* __restrict__ W, const float* __restrict__ bias,
    float* __restrict__ xsl, float* __restrict__ zl)
{
    int blk = blockIdx.x;            // 4096 blocks: b * 1024 + ptile
    int b   = blk >> 10;
    int p0  = (blk & 1023) << 2;     // 4 positions per block
    __shared__ float xt[64][4];
    int tid = threadIdx.x;
    {
        int c = tid >> 2, j = tid & 3;
        xt[c][j] = x[(((b << 6) + c) << 12) + p0 + j];
    }
    __syncthreads();
    int e = tid;                     // 0..255 output channel
    float bv = bias[e];
    float a0 = bv, a1 = bv, a2 = bv, a3 = bv;
    const float* wr = W + e * 64;
    #pragma unroll 8
    for (int c = 0; c < 64; ++c) {
        float wv = wr[c];
        a0 += wv * xt[c][0];
        a1 += wv * xt[c][1];
        a2 += wv * xt[c][2];
        a3 += wv * xt[c][3];
    }
    float* dst = (e < 128) ? xsl : zl;
    int ch = e & 127;
    float vals[4] = {a0, a1, a2, a3};
    #pragma unroll
    for (int j = 0; j < 4; ++j)
        dst[(((b << 12) + p0 + j) << 7) + ch] = vals[j];
}

// ---------------- K2: depthwise 3x3 conv + bias + SiLU -----------------------
__global__ __launch_bounds__(256) void k_conv(const float* __restrict__ xsl,
    const float* __restrict__ cw, const float* __restrict__ cb,
    float* __restrict__ xcl)
{
    int tid = threadIdx.x;
    int c  = tid & 127, pi = tid >> 7;
    int P  = blockIdx.x * 2 + pi;        // 0..B*L-1
    int b  = P >> 12, p = P & 4095;
    int r  = p >> 6,  cc = p & 63;
    float acc = cb[c];
    const float* wr = cw + c * 9;
    #pragma unroll
    for (int dy = -1; dy <= 1; ++dy) {
        int rr = r + dy;
        if ((unsigned)rr < 64u) {
            #pragma unroll
            for (int dx = -1; dx <= 1; ++dx) {
                int c2 = cc + dx;
                if ((unsigned)c2 < 64u)
                    acc += xsl[(((b << 12) + (rr << 6) + c2) << 7) + c]
                         * wr[(dy + 1) * 3 + (dx + 1)];
            }
        }
    }
    float s = acc / (1.f + __expf(-acc));   // SiLU
    xcl[(((b << 12) + p) << 7) + c] = s;
}

// -------- K3: gather u rows, x_proj (36 outs), delta_proj + softplus ---------
__global__ __launch_bounds__(192) void k_xproj(const float* __restrict__ xcl,
    const float* __restrict__ xpw, const float* __restrict__ dpw,
    const float* __restrict__ dpb,
    float* __restrict__ delta, float* __restrict__ du,
    float* __restrict__ Bm, float* __restrict__ Cm)
{
    __shared__ float uu[16][512];
    __shared__ float xdb[16][36];
    int tid = threadIdx.x;
    int b   = blockIdx.x >> 8;
    int t0  = (blockIdx.x & 255) << 4;   // 16 time steps per block

    for (int i = tid; i < 16 * 512; i += 192) {
        int tt = i >> 9, ch = i & 511;
        int g = ch >> 7, cd = ch & 127;
        int t = t0 + tt;
        int ta = tauf(t);
        int pos = (g == 0) ? t : (g == 1) ? ta : (g == 2) ? (4095 - t) : (4095 - ta);
        uu[tt][ch] = xcl[(((b << 12) + pos) << 7) + cd];
    }
    __syncthreads();

    for (int task = tid; task < 576; task += 192) {
        int tt = task / 36, j = task - tt * 36;
        const float4* u4 = (const float4*)uu[tt];
        const float4* w4 = (const float4*)(xpw + j * 512);
        float acc = 0.f;
        #pragma unroll 4
        for (int k = 0; k < 128; ++k) {
            float4 a = u4[k], w = w4[k];
            acc += a.x * w.x + a.y * w.y + a.z * w.z + a.w * w.w;
        }
        xdb[tt][j] = acc;
        int t = t0 + tt;
        if (j >= 20)      Cm[(((b << 12) + t) << 4) + j - 20] = acc;
        else if (j >= 4)  Bm[(((b << 12) + t) << 4) + j - 4]  = acc;
    }
    __syncthreads();

    for (int i = tid; i < 16 * 512; i += 192) {
        int tt = i >> 9, d = i & 511;
        float d0 = xdb[tt][0], d1 = xdb[tt][1], d2 = xdb[tt][2], d3 = xdb[tt][3];
        const float4 w = *(const float4*)(dpw + d * 4);
        float a = dpb[d] + d0 * w.x + d1 * w.y + d2 * w.z + d3 * w.w;
        float sp = fmaxf(a, 0.f) + log1pf(__expf(-fabsf(a)));   // softplus
        int idx = (((b << 12) + t0 + tt) << 9) + d;
        delta[idx] = sp;
        du[idx]    = sp * uu[tt][d];
    }
}

// ---------------- K4a: pass A — per-chunk local scan (h from 0) --------------
__global__ __launch_bounds__(256) void k_scanA(const float* __restrict__ delta,
    const float* __restrict__ du, const float* __restrict__ Bm,
    const float* __restrict__ Alog,
    float* __restrict__ hloc, float* __restrict__ Ssum)
{
    int tid  = threadIdx.x;
    int half = blockIdx.x & 1;
    int bc   = blockIdx.x >> 1;
    int b = bc >> 6, chunk = bc & 63;
    int d = (half << 8) + tid;

    float A[16], h[16];
    #pragma unroll
    for (int n = 0; n < 16; ++n) { A[n] = -__expf(Alog[(d << 4) + n]); h[n] = 0.f; }
    float S = 0.f;
    int t0 = chunk << 6;
    #pragma unroll 2
    for (int t = t0; t < t0 + TCH; ++t) {
        int base = (b << 12) + t;
        float dl = delta[(base << 9) + d];
        float uv = du[(base << 9) + d];
        const float4* Br = (const float4*)(Bm + (base << 4));
        float4 B0 = Br[0], B1 = Br[1], B2 = Br[2], B3 = Br[3];
        float Bv[16] = {B0.x,B0.y,B0.z,B0.w, B1.x,B1.y,B1.z,B1.w,
                        B2.x,B2.y,B2.z,B2.w, B3.x,B3.y,B3.z,B3.w};
        S += dl;
        #pragma unroll
        for (int n = 0; n < 16; ++n)
            h[n] = __expf(dl * A[n]) * h[n] + uv * Bv[n];
    }
    float4* ho = (float4*)(hloc + ((((b << 9) + d) * NCH + chunk) << 4));
    ho[0] = make_float4(h[0], h[1], h[2], h[3]);
    ho[1] = make_float4(h[4], h[5], h[6], h[7]);
    ho[2] = make_float4(h[8], h[9], h[10], h[11]);
    ho[3] = make_float4(h[12], h[13], h[14], h[15]);
    Ssum[((b << 9) + d) * NCH + chunk] = S;
}

// ------- K4c: combine chunk boundary states (in-place hloc -> hstart) --------
__global__ __launch_bounds__(256) void k_comb(float* __restrict__ hloc,
    const float* __restrict__ Ssum, const float* __restrict__ Alog)
{
    int g  = blockIdx.x * 256 + threadIdx.x;   // 0..32767 = (b*512+d)*16+n
    int n  = g & 15;
    int bd = g >> 4;
    int d  = bd & 511;
    float A = -__expf(Alog[(d << 4) + n]);
    float H = 0.f;
    for (int c = 0; c < NCH; ++c) {
        int idx = ((bd * NCH + c) << 4) + n;
        float hl = hloc[idx];
        float Sv = Ssum[bd * NCH + c];
        hloc[idx] = H;                          // H_start[c], overwrites local
        H = __expf(A * Sv) * H + hl;
    }
}

// ---------------- K4b: pass B — replay chunks with true h0, emit y -----------
__global__ __launch_bounds__(256) void k_scanB(const float* __restrict__ delta,
    const float* __restrict__ du, const float* __restrict__ Bm,
    const float* __restrict__ Cm, const float* __restrict__ Alog,
    const float* __restrict__ hstart, float* __restrict__ yb)
{
    int tid  = threadIdx.x;
    int half = blockIdx.x & 1;
    int bc   = blockIdx.x >> 1;
    int b = bc >> 6, chunk = bc & 63;
    int d = (half << 8) + tid;

    float A[16], h[16];
    #pragma unroll
    for (int n = 0; n < 16; ++n) A[n] = -__expf(Alog[(d << 4) + n]);
    const float4* hi = (const float4*)(hstart + ((((b << 9) + d) * NCH + chunk) << 4));
    float4 h0 = hi[0], h1 = hi[1], h2 = hi[2], h3 = hi[3];
    h[0]=h0.x; h[1]=h0.y; h[2]=h0.z; h[3]=h0.w;
    h[4]=h1.x; h[5]=h1.y; h[6]=h1.z; h[7]=h1.w;
    h[8]=h2.x; h[9]=h2.y; h[10]=h2.z; h[11]=h2.w;
    h[12]=h3.x; h[13]=h3.y; h[14]=h3.z; h[15]=h3.w;

    int t0 = chunk << 6;
    #pragma unroll 2
    for (int t = t0; t < t0 + TCH; ++t) {
        int base = (b << 12) + t;
        float dl = delta[(base << 9) + d];
        float uv = du[(base << 9) + d];
        const float4* Br = (const float4*)(Bm + (base << 4));
        const float4* Cr = (const float4*)(Cm + (base << 4));
        float4 B0 = Br[0], B1 = Br[1], B2 = Br[2], B3 = Br[3];
        float4 C0 = Cr[0], C1 = Cr[1], C2 = Cr[2], C3 = Cr[3];
        float Bv[16] = {B0.x,B0.y,B0.z,B0.w, B1.x,B1.y,B1.z,B1.w,
                        B2.x,B2.y,B2.z,B2.w, B3.x,B3.y,B3.z,B3.w};
        float Cv[16] = {C0.x,C0.y,C0.z,C0.w, C1.x,C1.y,C1.z,C1.w,
                        C2.x,C2.y,C2.z,C2.w, C3.x,C3.y,C3.z,C3.w};
        float y = 0.f;
        #pragma unroll
        for (int n = 0; n < 16; ++n) {
            h[n] = __expf(dl * A[n]) * h[n] + uv * Bv[n];
            y += h[n] * Cv[n];
        }
        yb[(base << 9) + d] = y;
    }
}

// ---- K5: gather 4 directions + D*u, LayerNorm, gate with SiLU(z), out_proj --
__global__ __launch_bounds__(256) void k_final(const float* __restrict__ yb,
    const float* __restrict__ xcl, const float* __restrict__ zl,
    const float* __restrict__ Dp, const float* __restrict__ lg,
    const float* __restrict__ lb, const float* __restrict__ Wout,
    float* __restrict__ out)
{
    __shared__ float m[4][128];
    int tid = threadIdx.x;
    int wv = tid >> 6, lane = tid & 63;
    int P = blockIdx.x * 4 + wv;
    int b = P >> 12, p = P & 4095;
    int ta = tauf(p);
    int base0 = ((b << 12) + p) << 9;
    int base1 = ((b << 12) + ta) << 9;
    int base2 = ((b << 12) + 4095 - p) << 9;
    int base3 = ((b << 12) + 4095 - ta) << 9;

    float v[2]; float s = 0.f, s2 = 0.f;
    #pragma unroll
    for (int k = 0; k < 2; ++k) {
        int dd = lane + (k << 6);
        float vv = yb[base0 + dd]
                 + yb[base1 + 128 + dd]
                 + yb[base2 + 256 + dd]
                 + yb[base3 + 384 + dd]
                 + xcl[(((b << 12) + p) << 7) + dd]
                   * (Dp[dd] + Dp[128 + dd] + Dp[256 + dd] + Dp[384 + dd]);
        v[k] = vv; s += vv; s2 += vv * vv;
    }
    #pragma unroll
    for (int o = 32; o; o >>= 1) { s += __shfl_xor(s, o); s2 += __shfl_xor(s2, o); }
    float mu   = s * (1.f / 128.f);
    float var  = s2 * (1.f / 128.f) - mu * mu;
    float rstd = rsqrtf(var + 1e-5f);
    #pragma unroll
    for (int k = 0; k < 2; ++k) {
        int dd = lane + (k << 6);
        float yn = (v[k] - mu) * rstd * lg[dd] + lb[dd];
        float zz = zl[(((b << 12) + p) << 7) + dd];
        m[wv][dd] = yn * (zz / (1.f + __expf(-zz)));
    }
    __syncthreads();
    int co = lane;
    const float4* wr = (const float4*)(Wout + co * 128);
    const float4* mm = (const float4*)m[wv];
    float acc = 0.f;
    #pragma unroll 8
    for (int k = 0; k < 32; ++k) {
        float4 w = wr[k], a = mm[k];
        acc += w.x * a.x + w.y * a.y + w.z * a.z + w.w * a.w;
    }
    out[(((b << 6) + co) << 12) + p] = acc;
}

// -----------------------------------------------------------------------------
extern "C" void kernel_launch(void* const* d_in, const int* in_sizes, int n_in,
                              void* d_out, int out_size, void* d_ws, size_t ws_size,
                              hipStream_t stream)
{
    const float* x    = (const float*)d_in[0];
    const float* ipw  = (const float*)d_in[1];
    const float* ipb  = (const float*)d_in[2];
    const float* cw   = (const float*)d_in[3];
    const float* cb   = (const float*)d_in[4];
    const float* xpw  = (const float*)d_in[5];
    const float* dpw  = (const float*)d_in[6];
    const float* dpb  = (const float*)d_in[7];
    const float* Alog = (const float*)d_in[8];
    const float* Dp   = (const float*)d_in[9];
    const float* lg   = (const float*)d_in[10];
    const float* lb   = (const float*)d_in[11];
    const float* wout = (const float*)d_in[12];

    float* ws    = (float*)d_ws;
    float* xsl   = ws;                    // B*L*128 = 2,097,152
    float* zl    = xsl  + 2097152;        // 2,097,152
    float* xcl   = zl   + 2097152;        // 2,097,152
    float* delta = xcl  + 2097152;        // B*L*512 = 8,388,608
    float* du    = delta + 8388608;       // 8,388,608
    float* Bmb   = du   + 8388608;        // B*L*16 = 262,144
    float* Cmb   = Bmb  + 262144;         // 262,144
    float* yb    = Cmb  + 262144;         // 8,388,608
    float* hloc  = yb   + 8388608;        // B*512*NCH*16 = 2,097,152
    float* Ssum  = hloc + 2097152;        // B*512*NCH = 131,072
    // total: 34,209,792 floats = ~130.5 MB

    float* out = (float*)d_out;

    hipLaunchKernelGGL(k_inproj, dim3(4096), dim3(256), 0, stream, x, ipw, ipb, xsl, zl);
    hipLaunchKernelGGL(k_conv,   dim3(8192), dim3(256), 0, stream, xsl, cw, cb, xcl);
    hipLaunchKernelGGL(k_xproj,  dim3(1024), dim3(192), 0, stream, xcl, xpw, dpw, dpb,
                       delta, du, Bmb, Cmb);
    hipLaunchKernelGGL(k_scanA,  dim3(512),  dim3(256), 0, stream, delta, du, Bmb, Alog,
                       hloc, Ssum);
    hipLaunchKernelGGL(k_comb,   dim3(128),  dim3(256), 0, stream, hloc, Ssum, Alog);
    hipLaunchKernelGGL(k_scanB,  dim3(512),  dim3(256), 0, stream, delta, du, Bmb, Cmb,
                       Alog, hloc, yb);
    hipLaunchKernelGGL(k_final,  dim3(4096), dim3(256), 0, stream, yb, xcl, zl, Dp,
                       lg, lb, wout, out);
}

// Round 4
// 342.649 us; speedup vs baseline: 1.3772x; 1.3772x over previous
//
#include <hip/hip_runtime.h>
#include <math.h>

// VMamba SS2D fused pipeline for MI355X.
// B=4, C_IN=64, D=128, D4=512, N=16, H=W=64, L=4096.
// Layouts: all intermediates channel-last (b, p, c) for coalescing.

#define LL   4096
#define NCH  128     // chunks
#define TCH  32      // chunk length

__device__ __forceinline__ int tauf(int t) { return ((t & 63) << 6) | (t >> 6); }

// ---------------- K1: in_proj GEMM  xz[b,p,e] = sum_c x[b,c,p]*W[e,c]+bias ----
__global__ __launch_bounds__(256) void k_inproj(const float* __restrict__ x,
    const float* __restrict__ W, const float* __restrict__ bias,
    float* __restrict__ xsl, float* __restrict__ zl)
{
    int blk = blockIdx.x;            // 4096 blocks: b * 1024 + ptile
    int b   = blk >> 10;
    int p0  = (blk & 1023) << 2;     // 4 positions per block
    __shared__ float xt[64][4];
    int tid = threadIdx.x;
    {
        int c = tid >> 2, j = tid & 3;
        xt[c][j] = x[(((b << 6) + c) << 12) + p0 + j];
    }
    __syncthreads();
    int e = tid;                     // 0..255 output channel
    float bv = bias[e];
    float a0 = bv, a1 = bv, a2 = bv, a3 = bv;
    const float* wr = W + e * 64;
    #pragma unroll 8
    for (int c = 0; c < 64; ++c) {
        float wv = wr[c];
        a0 += wv * xt[c][0];
        a1 += wv * xt[c][1];
        a2 += wv * xt[c][2];
        a3 += wv * xt[c][3];
    }
    float* dst = (e < 128) ? xsl : zl;
    int ch = e & 127;
    float vals[4] = {a0, a1, a2, a3};
    #pragma unroll
    for (int j = 0; j < 4; ++j)
        dst[(((b << 12) + p0 + j) << 7) + ch] = vals[j];
}

// ---------------- K2: depthwise 3x3 conv + bias + SiLU -----------------------
__global__ __launch_bounds__(256) void k_conv(const float* __restrict__ xsl,
    const float* __restrict__ cw, const float* __restrict__ cb,
    float* __restrict__ xcl)
{
    int tid = threadIdx.x;
    int c  = tid & 127, pi = tid >> 7;
    int P  = blockIdx.x * 2 + pi;        // 0..B*L-1
    int b  = P >> 12, p = P & 4095;
    int r  = p >> 6,  cc = p & 63;
    float acc = cb[c];
    const float* wr = cw + c * 9;
    #pragma unroll
    for (int dy = -1; dy <= 1; ++dy) {
        int rr = r + dy;
        if ((unsigned)rr < 64u) {
            #pragma unroll
            for (int dx = -1; dx <= 1; ++dx) {
                int c2 = cc + dx;
                if ((unsigned)c2 < 64u)
                    acc += xsl[(((b << 12) + (rr << 6) + c2) << 7) + c]
                         * wr[(dy + 1) * 3 + (dx + 1)];
            }
        }
    }
    float s = acc / (1.f + __expf(-acc));   // SiLU
    xcl[(((b << 12) + p) << 7) + c] = s;
}

// -------- K3a: P[r][jj] = sum_c xcl[r][c] * xpw[j][g*128+c], jj = g*36+j -----
// M=16384 rows, N=144 (4 dirs x 36), K=128. W quarter-rows in registers,
// 4-lane K-split adjacent in wave -> shfl_xor reduce (no LDS partials).
__global__ __launch_bounds__(576) void k_pgemm(const float* __restrict__ xcl,
    const float* __restrict__ xpw, float* __restrict__ P)
{
    __shared__ float ut[16][128];
    __shared__ float res[16][144];
    int tid = threadIdx.x;
    int q4  = tid & 3;              // K-quarter, adjacent lanes
    int jj  = tid >> 2;             // 0..143
    int r0  = blockIdx.x << 4;      // 16 rows per block

    // stage u tile (16 rows x 128 ch), coalesced
    if (tid < 512) {
        int row = tid >> 5, v = tid & 31;
        ((float4*)ut[row])[v] = ((const float4*)xcl)[((r0 + row) << 5) + v];
    }

    // W quarter-row into registers
    int j = jj % 36, g = jj / 36;
    const float4* wrow = (const float4*)(xpw + j * 512 + g * 128 + q4 * 32);
    float4 wreg[8];
    #pragma unroll
    for (int k = 0; k < 8; ++k) wreg[k] = wrow[k];

    __syncthreads();

    #pragma unroll 4
    for (int row = 0; row < 16; ++row) {
        const float4* ur = (const float4*)(ut[row] + q4 * 32);
        float s = 0.f;
        #pragma unroll
        for (int k = 0; k < 8; ++k) {
            float4 u4 = ur[k], w4 = wreg[k];
            s += u4.x * w4.x + u4.y * w4.y + u4.z * w4.z + u4.w * w4.w;
        }
        s += __shfl_xor(s, 1);
        s += __shfl_xor(s, 2);
        if (q4 == 0) res[row][jj] = s;
    }
    __syncthreads();

    #pragma unroll
    for (int k = 0; k < 4; ++k) {
        int idx = tid + k * 576;        // 2304 = 16*144
        int row = idx / 144, c = idx - row * 144;
        P[(r0 + row) * 144 + c] = res[row][c];
    }
}

// -------- K3b: x_dbl = sum of 4 gathered P rows; delta_proj+softplus ---------
__global__ __launch_bounds__(256) void k_xcomb(const float* __restrict__ P,
    const float* __restrict__ dpw, const float* __restrict__ dpb,
    float* __restrict__ delta, float* __restrict__ Bm, float* __restrict__ Cm)
{
    __shared__ float xdb[8][36];
    int tid = threadIdx.x;
    int b   = blockIdx.x >> 9;
    int t0  = (blockIdx.x & 511) << 3;     // 8 time steps per block

    for (int i = tid; i < 288; i += 256) {
        int tt = i / 36, j = i - tt * 36;
        int t  = t0 + tt, ta = tauf(t);
        int r0 = (b << 12) + t,        r1 = (b << 12) + ta;
        int r2 = (b << 12) + 4095 - t, r3 = (b << 12) + 4095 - ta;
        float s = P[r0 * 144 + j]       + P[r1 * 144 + 36 + j]
                + P[r2 * 144 + 72 + j]  + P[r3 * 144 + 108 + j];
        xdb[tt][j] = s;
        if (j >= 20)      Cm[((r0) << 4) + j - 20] = s;
        else if (j >= 4)  Bm[((r0) << 4) + j - 4]  = s;
    }
    __syncthreads();

    #pragma unroll
    for (int k = 0; k < 16; ++k) {
        int i  = tid + (k << 8);        // 8*512 = 4096 tasks
        int tt = i >> 9, d = i & 511;
        int t  = t0 + tt;
        float d0 = xdb[tt][0], d1 = xdb[tt][1], d2 = xdb[tt][2], d3 = xdb[tt][3];
        const float4 w = *(const float4*)(dpw + (d << 2));
        float a  = dpb[d] + d0 * w.x + d1 * w.y + d2 * w.z + d3 * w.w;
        float sp = fmaxf(a, 0.f) + log1pf(__expf(-fabsf(a)));   // softplus
        delta[(((b << 12) + t) << 9) + d] = sp;
    }
}

// ---------------- K4a: pass A — per-chunk local scan (h from 0) --------------
// du is computed on the fly: du = delta * xcl[b, pos_g(t), cd]
__global__ __launch_bounds__(256) void k_scanA(const float* __restrict__ delta,
    const float* __restrict__ xcl, const float* __restrict__ Bm,
    const float* __restrict__ Alog,
    float* __restrict__ hloc, float* __restrict__ Ssum)
{
    int tid  = threadIdx.x;
    int half = blockIdx.x & 1;
    int bc   = blockIdx.x >> 1;
    int b = bc >> 7, chunk = bc & 127;
    int d = (half << 8) + tid;
    int g = d >> 7, cd = d & 127;

    float A[16], h[16];
    #pragma unroll
    for (int n = 0; n < 16; ++n) { A[n] = -__expf(Alog[(d << 4) + n]); h[n] = 0.f; }
    float S = 0.f;
    int t0 = chunk << 5;
    for (int t = t0; t < t0 + TCH; ++t) {
        int base = (b << 12) + t;
        float dl = delta[(base << 9) + d];
        int ta  = tauf(t);
        int pos = (g == 0) ? t : (g == 1) ? ta : (g == 2) ? (4095 - t) : (4095 - ta);
        float uv = dl * xcl[(((b << 12) + pos) << 7) + cd];
        const float4* Br = (const float4*)(Bm + (base << 4));
        float4 B0 = Br[0], B1 = Br[1], B2 = Br[2], B3 = Br[3];
        float Bv[16] = {B0.x,B0.y,B0.z,B0.w, B1.x,B1.y,B1.z,B1.w,
                        B2.x,B2.y,B2.z,B2.w, B3.x,B3.y,B3.z,B3.w};
        S += dl;
        #pragma unroll
        for (int n = 0; n < 16; ++n)
            h[n] = __expf(dl * A[n]) * h[n] + uv * Bv[n];
    }
    float4* ho = (float4*)(hloc + ((((b << 9) + d) * NCH + chunk) << 4));
    ho[0] = make_float4(h[0], h[1], h[2], h[3]);
    ho[1] = make_float4(h[4], h[5], h[6], h[7]);
    ho[2] = make_float4(h[8], h[9], h[10], h[11]);
    ho[3] = make_float4(h[12], h[13], h[14], h[15]);
    Ssum[((b << 9) + d) * NCH + chunk] = S;
}

// ------- K4c: combine chunk boundary states (in-place hloc -> hstart) --------
// Batched loads (16 chunks at a time) + precomputed exp factors so only the
// irreducible 128-step fma chain is serial.
__global__ __launch_bounds__(256) void k_comb(float* __restrict__ hloc,
    const float* __restrict__ Ssum, const float* __restrict__ Alog)
{
    int gidx = blockIdx.x * 256 + threadIdx.x;   // 0..32767 = (b*512+d)*16+n
    int n  = gidx & 15;
    int bd = gidx >> 4;
    int d  = bd & 511;
    float A = -__expf(Alog[(d << 4) + n]);
    float H = 0.f;
    for (int c0 = 0; c0 < NCH; c0 += 16) {
        float hl[16], ef[16];
        #pragma unroll
        for (int j = 0; j < 16; ++j) {
            hl[j] = hloc[((bd * NCH + c0 + j) << 4) + n];
            ef[j] = Ssum[bd * NCH + c0 + j];
        }
        #pragma unroll
        for (int j = 0; j < 16; ++j) ef[j] = __expf(A * ef[j]);
        #pragma unroll
        for (int j = 0; j < 16; ++j) {
            hloc[((bd * NCH + c0 + j) << 4) + n] = H;   // H_start[chunk]
            H = ef[j] * H + hl[j];
        }
    }
}

// ---------------- K4b: pass B — replay chunks with true h0, emit y -----------
__global__ __launch_bounds__(256) void k_scanB(const float* __restrict__ delta,
    const float* __restrict__ xcl, const float* __restrict__ Bm,
    const float* __restrict__ Cm, const float* __restrict__ Alog,
    const float* __restrict__ hstart, float* __restrict__ yb)
{
    int tid  = threadIdx.x;
    int half = blockIdx.x & 1;
    int bc   = blockIdx.x >> 1;
    int b = bc >> 7, chunk = bc & 127;
    int d = (half << 8) + tid;
    int g = d >> 7, cd = d & 127;

    float A[16], h[16];
    #pragma unroll
    for (int n = 0; n < 16; ++n) A[n] = -__expf(Alog[(d << 4) + n]);
    const float4* hi = (const float4*)(hstart + ((((b << 9) + d) * NCH + chunk) << 4));
    float4 h0 = hi[0], h1 = hi[1], h2 = hi[2], h3 = hi[3];
    h[0]=h0.x; h[1]=h0.y; h[2]=h0.z; h[3]=h0.w;
    h[4]=h1.x; h[5]=h1.y; h[6]=h1.z; h[7]=h1.w;
    h[8]=h2.x; h[9]=h2.y; h[10]=h2.z; h[11]=h2.w;
    h[12]=h3.x; h[13]=h3.y; h[14]=h3.z; h[15]=h3.w;

    int t0 = chunk << 5;
    for (int t = t0; t < t0 + TCH; ++t) {
        int base = (b << 12) + t;
        float dl = delta[(base << 9) + d];
        int ta  = tauf(t);
        int pos = (g == 0) ? t : (g == 1) ? ta : (g == 2) ? (4095 - t) : (4095 - ta);
        float uv = dl * xcl[(((b << 12) + pos) << 7) + cd];
        const float4* Br = (const float4*)(Bm + (base << 4));
        const float4* Cr = (const float4*)(Cm + (base << 4));
        float4 B0 = Br[0], B1 = Br[1], B2 = Br[2], B3 = Br[3];
        float4 C0 = Cr[0], C1 = Cr[1], C2 = Cr[2], C3 = Cr[3];
        float Bv[16] = {B0.x,B0.y,B0.z,B0.w, B1.x,B1.y,B1.z,B1.w,
                        B2.x,B2.y,B2.z,B2.w, B3.x,B3.y,B3.z,B3.w};
        float Cv[16] = {C0.x,C0.y,C0.z,C0.w, C1.x,C1.y,C1.z,C1.w,
                        C2.x,C2.y,C2.z,C2.w, C3.x,C3.y,C3.z,C3.w};
        float y = 0.f;
        #pragma unroll
        for (int n = 0; n < 16; ++n) {
            h[n] = __expf(dl * A[n]) * h[n] + uv * Bv[n];
            y += h[n] * Cv[n];
        }
        yb[(base << 9) + d] = y;
    }
}

// ---- K5: gather 4 directions + D*u, LayerNorm, gate with SiLU(z), out_proj --
__global__ __launch_bounds__(256) void k_final(const float* __restrict__ yb,
    const float* __restrict__ xcl, const float* __restrict__ zl,
    const float* __restrict__ Dp, const float* __restrict__ lg,
    const float* __restrict__ lb, const float* __restrict__ Wout,
    float* __restrict__ out)
{
    __shared__ float m[4][128];
    int tid = threadIdx.x;
    int wv = tid >> 6, lane = tid & 63;
    int P = blockIdx.x * 4 + wv;
    int b = P >> 12, p = P & 4095;
    int ta = tauf(p);
    int base0 = ((b << 12) + p) << 9;
    int base1 = ((b << 12) + ta) << 9;
    int base2 = ((b << 12) + 4095 - p) << 9;
    int base3 = ((b << 12) + 4095 - ta) << 9;

    float v[2]; float s = 0.f, s2 = 0.f;
    #pragma unroll
    for (int k = 0; k < 2; ++k) {
        int dd = lane + (k << 6);
        float vv = yb[base0 + dd]
                 + yb[base1 + 128 + dd]
                 + yb[base2 + 256 + dd]
                 + yb[base3 + 384 + dd]
                 + xcl[(((b << 12) + p) << 7) + dd]
                   * (Dp[dd] + Dp[128 + dd] + Dp[256 + dd] + Dp[384 + dd]);
        v[k] = vv; s += vv; s2 += vv * vv;
    }
    #pragma unroll
    for (int o = 32; o; o >>= 1) { s += __shfl_xor(s, o); s2 += __shfl_xor(s2, o); }
    float mu   = s * (1.f / 128.f);
    float var  = s2 * (1.f / 128.f) - mu * mu;
    float rstd = rsqrtf(var + 1e-5f);
    #pragma unroll
    for (int k = 0; k < 2; ++k) {
        int dd = lane + (k << 6);
        float yn = (v[k] - mu) * rstd * lg[dd] + lb[dd];
        float zz = zl[(((b << 12) + p) << 7) + dd];
        m[wv][dd] = yn * (zz / (1.f + __expf(-zz)));
    }
    __syncthreads();
    int co = lane;
    const float4* wr = (const float4*)(Wout + co * 128);
    const float4* mm = (const float4*)m[wv];
    float acc = 0.f;
    #pragma unroll 8
    for (int k = 0; k < 32; ++k) {
        float4 w = wr[k], a = mm[k];
        acc += w.x * a.x + w.y * a.y + w.z * a.z + w.w * a.w;
    }
    out[(((b << 6) + co) << 12) + p] = acc;
}

// -----------------------------------------------------------------------------
extern "C" void kernel_launch(void* const* d_in, const int* in_sizes, int n_in,
                              void* d_out, int out_size, void* d_ws, size_t ws_size,
                              hipStream_t stream)
{
    const float* x    = (const float*)d_in[0];
    const float* ipw  = (const float*)d_in[1];
    const float* ipb  = (const float*)d_in[2];
    const float* cw   = (const float*)d_in[3];
    const float* cb   = (const float*)d_in[4];
    const float* xpw  = (const float*)d_in[5];
    const float* dpw  = (const float*)d_in[6];
    const float* dpb  = (const float*)d_in[7];
    const float* Alog = (const float*)d_in[8];
    const float* Dp   = (const float*)d_in[9];
    const float* lg   = (const float*)d_in[10];
    const float* lb   = (const float*)d_in[11];
    const float* wout = (const float*)d_in[12];

    float* ws    = (float*)d_ws;
    float* xsl   = ws;                    // B*L*128 = 2,097,152
    float* zl    = xsl  + 2097152;        // 2,097,152
    float* xcl   = zl   + 2097152;        // 2,097,152
    float* delta = xcl  + 2097152;        // B*L*512 = 8,388,608
    float* Bmb   = delta + 8388608;       // B*L*16 = 262,144
    float* Cmb   = Bmb  + 262144;         // 262,144
    float* yb    = Cmb  + 262144;         // 8,388,608
    float* hloc  = yb   + 8388608;        // B*512*NCH*16 = 4,194,304
    float* Ssum  = hloc + 4194304;        // B*512*NCH = 262,144
    // total: ~28.3M floats = ~113 MB
    float* Pbuf  = yb;                    // 16384*144 = 2,359,296  (aliases yb;
                                          // dead before k_scanB writes yb)

    float* out = (float*)d_out;

    hipLaunchKernelGGL(k_inproj, dim3(4096), dim3(256), 0, stream, x, ipw, ipb, xsl, zl);
    hipLaunchKernelGGL(k_conv,   dim3(8192), dim3(256), 0, stream, xsl, cw, cb, xcl);
    hipLaunchKernelGGL(k_pgemm,  dim3(1024), dim3(576), 0, stream, xcl, xpw, Pbuf);
    hipLaunchKernelGGL(k_xcomb,  dim3(2048), dim3(256), 0, stream, Pbuf, dpw, dpb,
                       delta, Bmb, Cmb);
    hipLaunchKernelGGL(k_scanA,  dim3(1024), dim3(256), 0, stream, delta, xcl, Bmb,
                       Alog, hloc, Ssum);
    hipLaunchKernelGGL(k_comb,   dim3(128),  dim3(256), 0, stream, hloc, Ssum, Alog);
    hipLaunchKernelGGL(k_scanB,  dim3(1024), dim3(256), 0, stream, delta, xcl, Bmb,
                       Cmb, Alog, hloc, yb);
    hipLaunchKernelGGL(k_final,  dim3(4096), dim3(256), 0, stream, yb, xcl, zl, Dp,
                       lg, lb, wout, out);
}

// Round 5
// 265.438 us; speedup vs baseline: 1.7778x; 1.2909x over previous
//
#include <hip/hip_runtime.h>
#include <math.h>

// VMamba SS2D fused pipeline for MI355X.
// B=4, C_IN=64, D=128, D4=512, N=16, H=W=64, L=4096.
// Layouts: all intermediates channel-last (b, p, c) for coalescing.

#define LL   4096
#define NCH  128     // chunks
#define TCH  32      // chunk length

__device__ __forceinline__ int tauf(int t) { return ((t & 63) << 6) | (t >> 6); }

// ---------------- K1: in_proj GEMM  xz[b,p,e] = sum_c x[b,c,p]*W[e,c]+bias ----
// 16 positions per block; W row (64 f) in regs amortized; x read wave-uniform.
__global__ __launch_bounds__(256) void k_inproj(const float* __restrict__ x,
    const float* __restrict__ W, const float* __restrict__ bias,
    float* __restrict__ xsl, float* __restrict__ zl)
{
    int tid = threadIdx.x;
    int b   = blockIdx.x >> 8;
    int p0  = (blockIdx.x & 255) << 4;
    int e   = tid;

    float wr[64];
    {
        const float4* wrow = (const float4*)(W + (e << 6));
        #pragma unroll
        for (int k = 0; k < 16; ++k) ((float4*)wr)[k] = wrow[k];
    }
    float acc[16];
    float bv = bias[e];
    #pragma unroll
    for (int j = 0; j < 16; ++j) acc[j] = bv;

    const float* xb = x + ((b << 6) << 12) + p0;
    #pragma unroll
    for (int c = 0; c < 64; ++c) {
        const float* xr = xb + (c << 12);      // wave-uniform address
        float w = wr[c];
        #pragma unroll
        for (int j = 0; j < 16; ++j) acc[j] += w * xr[j];
    }

    float* dst = (e < 128) ? xsl : zl;
    int ch = e & 127;
    #pragma unroll
    for (int j = 0; j < 16; ++j)
        dst[(((b << 12) + p0 + j) << 7) + ch] = acc[j];
}

// ---------------- K2: depthwise 3x3 conv + bias + SiLU -----------------------
// 4 positions/thread (one row), sliding 6-col window, weights via LDS.
__global__ __launch_bounds__(256) void k_conv(const float* __restrict__ xsl,
    const float* __restrict__ cw, const float* __restrict__ cb,
    float* __restrict__ xcl)
{
    __shared__ float wlds[1152];               // 128 ch x 9
    int tid = threadIdx.x;
    for (int i = tid; i < 1152; i += 256) wlds[i] = cw[i];
    int c    = tid & 127, half = tid >> 7;
    int P0   = blockIdx.x << 3;                // 8 positions per block, one row
    int b    = P0 >> 12;
    int p0   = (P0 & 4095) + (half << 2);      // 4 positions per thread
    int r    = p0 >> 6, c0 = p0 & 63;
    __syncthreads();

    float w[9];
    #pragma unroll
    for (int k = 0; k < 9; ++k) w[k] = wlds[c * 9 + k];
    float bv = cb[c];
    float acc[4] = {bv, bv, bv, bv};

    #pragma unroll
    for (int dy = -1; dy <= 1; ++dy) {
        int rr = r + dy;
        if ((unsigned)rr < 64u) {
            float v[6];
            #pragma unroll
            for (int o = 0; o < 6; ++o) {
                int cc = c0 + o - 1;
                v[o] = ((unsigned)cc < 64u)
                     ? xsl[(((b << 12) + (rr << 6) + cc) << 7) + c] : 0.f;
            }
            int wb = (dy + 1) * 3;
            #pragma unroll
            for (int j = 0; j < 4; ++j)
                acc[j] += w[wb] * v[j] + w[wb + 1] * v[j + 1] + w[wb + 2] * v[j + 2];
        }
    }
    #pragma unroll
    for (int j = 0; j < 4; ++j) {
        float a = acc[j];
        xcl[(((b << 12) + p0 + j) << 7) + c] = a / (1.f + __expf(-a));
    }
}

// -------- K3a: P[r][jj] = sum_c xcl[r][c] * xpw[j][g*128+c], jj = g*36+j -----
// M=16384 rows, N=144 (4 dirs x 36), K=128. W quarter-rows in registers,
// 4-lane K-split adjacent in wave -> shfl_xor reduce (no LDS partials).
__global__ __launch_bounds__(576) void k_pgemm(const float* __restrict__ xcl,
    const float* __restrict__ xpw, float* __restrict__ P)
{
    __shared__ float ut[16][128];
    __shared__ float res[16][144];
    int tid = threadIdx.x;
    int q4  = tid & 3;              // K-quarter, adjacent lanes
    int jj  = tid >> 2;             // 0..143
    int r0  = blockIdx.x << 4;      // 16 rows per block

    // stage u tile (16 rows x 128 ch), coalesced
    if (tid < 512) {
        int row = tid >> 5, v = tid & 31;
        ((float4*)ut[row])[v] = ((const float4*)xcl)[((r0 + row) << 5) + v];
    }

    // W quarter-row into registers
    int j = jj % 36, g = jj / 36;
    const float4* wrow = (const float4*)(xpw + j * 512 + g * 128 + q4 * 32);
    float4 wreg[8];
    #pragma unroll
    for (int k = 0; k < 8; ++k) wreg[k] = wrow[k];

    __syncthreads();

    #pragma unroll 4
    for (int row = 0; row < 16; ++row) {
        const float4* ur = (const float4*)(ut[row] + q4 * 32);
        float s = 0.f;
        #pragma unroll
        for (int k = 0; k < 8; ++k) {
            float4 u4 = ur[k], w4 = wreg[k];
            s += u4.x * w4.x + u4.y * w4.y + u4.z * w4.z + u4.w * w4.w;
        }
        s += __shfl_xor(s, 1);
        s += __shfl_xor(s, 2);
        if (q4 == 0) res[row][jj] = s;
    }
    __syncthreads();

    #pragma unroll
    for (int k = 0; k < 4; ++k) {
        int idx = tid + k * 576;        // 2304 = 16*144
        int row = idx / 144, c = idx - row * 144;
        P[(r0 + row) * 144 + c] = res[row][c];
    }
}

// -------- K3b: x_dbl = sum of 4 gathered P rows; delta_proj+softplus ---------
__global__ __launch_bounds__(256) void k_xcomb(const float* __restrict__ P,
    const float* __restrict__ dpw, const float* __restrict__ dpb,
    float* __restrict__ delta, float* __restrict__ Bm, float* __restrict__ Cm)
{
    __shared__ float xdb[8][36];
    int tid = threadIdx.x;
    int b   = blockIdx.x >> 9;
    int t0  = (blockIdx.x & 511) << 3;     // 8 time steps per block

    for (int i = tid; i < 288; i += 256) {
        int tt = i / 36, j = i - tt * 36;
        int t  = t0 + tt, ta = tauf(t);
        int r0 = (b << 12) + t,        r1 = (b << 12) + ta;
        int r2 = (b << 12) + 4095 - t, r3 = (b << 12) + 4095 - ta;
        float s = P[r0 * 144 + j]       + P[r1 * 144 + 36 + j]
                + P[r2 * 144 + 72 + j]  + P[r3 * 144 + 108 + j];
        xdb[tt][j] = s;
        if (j >= 20)      Cm[((r0) << 4) + j - 20] = s;
        else if (j >= 4)  Bm[((r0) << 4) + j - 4]  = s;
    }
    __syncthreads();

    #pragma unroll
    for (int k = 0; k < 16; ++k) {
        int i  = tid + (k << 8);        // 8*512 = 4096 tasks
        int tt = i >> 9, d = i & 511;
        int t  = t0 + tt;
        float d0 = xdb[tt][0], d1 = xdb[tt][1], d2 = xdb[tt][2], d3 = xdb[tt][3];
        const float4 w = *(const float4*)(dpw + (d << 2));
        float a  = dpb[d] + d0 * w.x + d1 * w.y + d2 * w.z + d3 * w.w;
        float sp = fmaxf(a, 0.f) + log1pf(__expf(-fabsf(a)));   // softplus
        delta[(((b << 12) + t) << 9) + d] = sp;
    }
}

// ---------------- K4a: pass A — per-chunk local scan (h from 0) --------------
// du is computed on the fly: du = delta * xcl[b, pos_g(t), cd]
__global__ __launch_bounds__(256) void k_scanA(const float* __restrict__ delta,
    const float* __restrict__ xcl, const float* __restrict__ Bm,
    const float* __restrict__ Alog,
    float* __restrict__ hloc, float* __restrict__ Ssum)
{
    int tid  = threadIdx.x;
    int half = blockIdx.x & 1;
    int bc   = blockIdx.x >> 1;
    int b = bc >> 7, chunk = bc & 127;
    int d = (half << 8) + tid;
    int g = d >> 7, cd = d & 127;

    float A[16], h[16];
    #pragma unroll
    for (int n = 0; n < 16; ++n) { A[n] = -__expf(Alog[(d << 4) + n]); h[n] = 0.f; }
    float S = 0.f;
    int t0 = chunk << 5;
    for (int t = t0; t < t0 + TCH; ++t) {
        int base = (b << 12) + t;
        float dl = delta[(base << 9) + d];
        int ta  = tauf(t);
        int pos = (g == 0) ? t : (g == 1) ? ta : (g == 2) ? (4095 - t) : (4095 - ta);
        float uv = dl * xcl[(((b << 12) + pos) << 7) + cd];
        const float4* Br = (const float4*)(Bm + (base << 4));
        float4 B0 = Br[0], B1 = Br[1], B2 = Br[2], B3 = Br[3];
        float Bv[16] = {B0.x,B0.y,B0.z,B0.w, B1.x,B1.y,B1.z,B1.w,
                        B2.x,B2.y,B2.z,B2.w, B3.x,B3.y,B3.z,B3.w};
        S += dl;
        #pragma unroll
        for (int n = 0; n < 16; ++n)
            h[n] = __expf(dl * A[n]) * h[n] + uv * Bv[n];
    }
    float4* ho = (float4*)(hloc + ((((b << 9) + d) * NCH + chunk) << 4));
    ho[0] = make_float4(h[0], h[1], h[2], h[3]);
    ho[1] = make_float4(h[4], h[5], h[6], h[7]);
    ho[2] = make_float4(h[8], h[9], h[10], h[11]);
    ho[3] = make_float4(h[12], h[13], h[14], h[15]);
    Ssum[((b << 9) + d) * NCH + chunk] = S;
}

// ------- K4c: combine chunk boundary states (in-place hloc -> hstart) --------
// Batched loads (16 chunks at a time) + precomputed exp factors so only the
// irreducible 128-step fma chain is serial.
__global__ __launch_bounds__(256) void k_comb(float* __restrict__ hloc,
    const float* __restrict__ Ssum, const float* __restrict__ Alog)
{
    int gidx = blockIdx.x * 256 + threadIdx.x;   // 0..32767 = (b*512+d)*16+n
    int n  = gidx & 15;
    int bd = gidx >> 4;
    int d  = bd & 511;
    float A = -__expf(Alog[(d << 4) + n]);
    float H = 0.f;
    for (int c0 = 0; c0 < NCH; c0 += 16) {
        float hl[16], ef[16];
        #pragma unroll
        for (int j = 0; j < 16; ++j) {
            hl[j] = hloc[((bd * NCH + c0 + j) << 4) + n];
            ef[j] = Ssum[bd * NCH + c0 + j];
        }
        #pragma unroll
        for (int j = 0; j < 16; ++j) ef[j] = __expf(A * ef[j]);
        #pragma unroll
        for (int j = 0; j < 16; ++j) {
            hloc[((bd * NCH + c0 + j) << 4) + n] = H;   // H_start[chunk]
            H = ef[j] * H + hl[j];
        }
    }
}

// ---------------- K4b: pass B — replay chunks with true h0, emit y -----------
__global__ __launch_bounds__(256) void k_scanB(const float* __restrict__ delta,
    const float* __restrict__ xcl, const float* __restrict__ Bm,
    const float* __restrict__ Cm, const float* __restrict__ Alog,
    const float* __restrict__ hstart, float* __restrict__ yb)
{
    int tid  = threadIdx.x;
    int half = blockIdx.x & 1;
    int bc   = blockIdx.x >> 1;
    int b = bc >> 7, chunk = bc & 127;
    int d = (half << 8) + tid;
    int g = d >> 7, cd = d & 127;

    float A[16], h[16];
    #pragma unroll
    for (int n = 0; n < 16; ++n) A[n] = -__expf(Alog[(d << 4) + n]);
    const float4* hi = (const float4*)(hstart + ((((b << 9) + d) * NCH + chunk) << 4));
    float4 h0 = hi[0], h1 = hi[1], h2 = hi[2], h3 = hi[3];
    h[0]=h0.x; h[1]=h0.y; h[2]=h0.z; h[3]=h0.w;
    h[4]=h1.x; h[5]=h1.y; h[6]=h1.z; h[7]=h1.w;
    h[8]=h2.x; h[9]=h2.y; h[10]=h2.z; h[11]=h2.w;
    h[12]=h3.x; h[13]=h3.y; h[14]=h3.z; h[15]=h3.w;

    int t0 = chunk << 5;
    for (int t = t0; t < t0 + TCH; ++t) {
        int base = (b << 12) + t;
        float dl = delta[(base << 9) + d];
        int ta  = tauf(t);
        int pos = (g == 0) ? t : (g == 1) ? ta : (g == 2) ? (4095 - t) : (4095 - ta);
        float uv = dl * xcl[(((b << 12) + pos) << 7) + cd];
        const float4* Br = (const float4*)(Bm + (base << 4));
        const float4* Cr = (const float4*)(Cm + (base << 4));
        float4 B0 = Br[0], B1 = Br[1], B2 = Br[2], B3 = Br[3];
        float4 C0 = Cr[0], C1 = Cr[1], C2 = Cr[2], C3 = Cr[3];
        float Bv[16] = {B0.x,B0.y,B0.z,B0.w, B1.x,B1.y,B1.z,B1.w,
                        B2.x,B2.y,B2.z,B2.w, B3.x,B3.y,B3.z,B3.w};
        float Cv[16] = {C0.x,C0.y,C0.z,C0.w, C1.x,C1.y,C1.z,C1.w,
                        C2.x,C2.y,C2.z,C2.w, C3.x,C3.y,C3.z,C3.w};
        float y = 0.f;
        #pragma unroll
        for (int n = 0; n < 16; ++n) {
            h[n] = __expf(dl * A[n]) * h[n] + uv * Bv[n];
            y += h[n] * Cv[n];
        }
        yb[(base << 9) + d] = y;
    }
}

// ---- K5: gather 4 dirs + D*u, LayerNorm, gate SiLU(z), out_proj (16 pos/blk)
__global__ __launch_bounds__(256) void k_final(const float* __restrict__ yb,
    const float* __restrict__ xcl, const float* __restrict__ zl,
    const float* __restrict__ Dp, const float* __restrict__ lg,
    const float* __restrict__ lb, const float* __restrict__ Wout,
    float* __restrict__ out)
{
    __shared__ float mt[16][4][36];   // gated m, quarter-padded (conflict-free)
    __shared__ float res[64][17];
    int tid = threadIdx.x;
    int b   = blockIdx.x >> 8;
    int p0  = (blockIdx.x & 255) << 4;
    int wv  = tid >> 6, lane = tid & 63;

    // W quarter-row in regs, loaded once per block (amortized over 16 pos)
    int co = tid >> 2, q4 = tid & 3;
    float4 wq[8];
    {
        const float4* wrow = (const float4*)(Wout + (co << 7) + (q4 << 5));
        #pragma unroll
        for (int k = 0; k < 8; ++k) wq[k] = wrow[k];
    }

    // phase 1: each wave computes LN+gate for 4 positions
    #pragma unroll
    for (int q = 0; q < 4; ++q) {
        int pos = (wv << 2) + q;
        int p = p0 + pos;
        int ta = tauf(p);
        int base0 = ((b << 12) + p) << 9;
        int base1 = ((b << 12) + ta) << 9;
        int base2 = ((b << 12) + 4095 - p) << 9;
        int base3 = ((b << 12) + 4095 - ta) << 9;

        float v[2]; float s = 0.f, s2 = 0.f;
        #pragma unroll
        for (int k = 0; k < 2; ++k) {
            int dd = lane + (k << 6);
            float vv = yb[base0 + dd]
                     + yb[base1 + 128 + dd]
                     + yb[base2 + 256 + dd]
                     + yb[base3 + 384 + dd]
                     + xcl[(((b << 12) + p) << 7) + dd]
                       * (Dp[dd] + Dp[128 + dd] + Dp[256 + dd] + Dp[384 + dd]);
            v[k] = vv; s += vv; s2 += vv * vv;
        }
        #pragma unroll
        for (int o = 32; o; o >>= 1) { s += __shfl_xor(s, o); s2 += __shfl_xor(s2, o); }
        float mu   = s * (1.f / 128.f);
        float var  = s2 * (1.f / 128.f) - mu * mu;
        float rstd = rsqrtf(var + 1e-5f);
        #pragma unroll
        for (int k = 0; k < 2; ++k) {
            int dd = lane + (k << 6);
            float yn = (v[k] - mu) * rstd * lg[dd] + lb[dd];
            float zz = zl[(((b << 12) + p) << 7) + dd];
            mt[pos][dd >> 5][dd & 31] = yn * (zz / (1.f + __expf(-zz)));
        }
    }
    __syncthreads();

    // phase 2: out[co][p0+pos] = sum_k mt[pos][k] * Wout[co][k]
    #pragma unroll 4
    for (int pos = 0; pos < 16; ++pos) {
        const float* mq = &mt[pos][q4][0];
        float s = 0.f;
        #pragma unroll
        for (int k = 0; k < 8; ++k) {
            float4 m4 = *(const float4*)&mq[k << 2];
            float4 w4 = wq[k];
            s += m4.x * w4.x + m4.y * w4.y + m4.z * w4.z + m4.w * w4.w;
        }
        s += __shfl_xor(s, 1);
        s += __shfl_xor(s, 2);
        if (q4 == 0) res[co][pos] = s;
    }
    __syncthreads();

    // coalesced-ish write: 4 threads per channel, float4 each (64B line per co)
    {
        int co2 = tid >> 2, part = tid & 3;
        float4 o4;
        o4.x = res[co2][(part << 2) + 0];
        o4.y = res[co2][(part << 2) + 1];
        o4.z = res[co2][(part << 2) + 2];
        o4.w = res[co2][(part << 2) + 3];
        *(float4*)&out[(((b << 6) + co2) << 12) + p0 + (part << 2)] = o4;
    }
}

// -----------------------------------------------------------------------------
extern "C" void kernel_launch(void* const* d_in, const int* in_sizes, int n_in,
                              void* d_out, int out_size, void* d_ws, size_t ws_size,
                              hipStream_t stream)
{
    const float* x    = (const float*)d_in[0];
    const float* ipw  = (const float*)d_in[1];
    const float* ipb  = (const float*)d_in[2];
    const float* cw   = (const float*)d_in[3];
    const float* cb   = (const float*)d_in[4];
    const float* xpw  = (const float*)d_in[5];
    const float* dpw  = (const float*)d_in[6];
    const float* dpb  = (const float*)d_in[7];
    const float* Alog = (const float*)d_in[8];
    const float* Dp   = (const float*)d_in[9];
    const float* lg   = (const float*)d_in[10];
    const float* lb   = (const float*)d_in[11];
    const float* wout = (const float*)d_in[12];

    float* ws    = (float*)d_ws;
    float* xsl   = ws;                    // B*L*128 = 2,097,152
    float* zl    = xsl  + 2097152;        // 2,097,152
    float* xcl   = zl   + 2097152;        // 2,097,152
    float* delta = xcl  + 2097152;        // B*L*512 = 8,388,608
    float* Bmb   = delta + 8388608;       // B*L*16 = 262,144
    float* Cmb   = Bmb  + 262144;         // 262,144
    float* yb    = Cmb  + 262144;         // 8,388,608
    float* hloc  = yb   + 8388608;        // B*512*NCH*16 = 4,194,304
    float* Ssum  = hloc + 4194304;        // B*512*NCH = 262,144
    float* Pbuf  = yb;                    // 16384*144 (aliases yb; dead before
                                          // k_scanB writes yb)

    float* out = (float*)d_out;

    hipLaunchKernelGGL(k_inproj, dim3(1024), dim3(256), 0, stream, x, ipw, ipb, xsl, zl);
    hipLaunchKernelGGL(k_conv,   dim3(2048), dim3(256), 0, stream, xsl, cw, cb, xcl);
    hipLaunchKernelGGL(k_pgemm,  dim3(1024), dim3(576), 0, stream, xcl, xpw, Pbuf);
    hipLaunchKernelGGL(k_xcomb,  dim3(2048), dim3(256), 0, stream, Pbuf, dpw, dpb,
                       delta, Bmb, Cmb);
    hipLaunchKernelGGL(k_scanA,  dim3(1024), dim3(256), 0, stream, delta, xcl, Bmb,
                       Alog, hloc, Ssum);
    hipLaunchKernelGGL(k_comb,   dim3(128),  dim3(256), 0, stream, hloc, Ssum, Alog);
    hipLaunchKernelGGL(k_scanB,  dim3(1024), dim3(256), 0, stream, delta, xcl, Bmb,
                       Cmb, Alog, hloc, yb);
    hipLaunchKernelGGL(k_final,  dim3(1024), dim3(256), 0, stream, yb, xcl, zl, Dp,
                       lg, lb, wout, out);
}